// Round 35
// baseline (176.741 us; speedup 1.0000x reference)
//
#include <hip/hip_runtime.h>
#include <cstdint>
#include <cstddef>

typedef __attribute__((ext_vector_type(8))) short bf16x8;
typedef __attribute__((ext_vector_type(4))) float f32x4;
typedef __attribute__((ext_vector_type(4))) unsigned short us4;
typedef __attribute__((ext_vector_type(8))) unsigned short us8;

#define NHEADS 12
#define BATCH 8
#define SEQ 1024
#define HDIM 64
#define CDIM 768
#define QKV_N 2304
#define BHND ((size_t)(BATCH) * NHEADS * SEQ * HDIM)   // 6291456
#define NX   ((size_t)8192 * 768)                      // 6291456
#define NWQ  ((size_t)768 * 2304)                      // 1769472
#define NWP  ((size_t)768 * 768)                       // 589824

__device__ __forceinline__ unsigned short f2bf(float f) {
    union { float f; uint32_t u; } v; v.f = f;
    uint32_t u = v.u;
    u += 0x7fffu + ((u >> 16) & 1u);   // RNE
    return (unsigned short)(u >> 16);
}

__device__ __forceinline__ void gl_lds16(const unsigned short* g, unsigned short* l) {
    __builtin_amdgcn_global_load_lds(
        (const __attribute__((address_space(1))) void*)g,
        (__attribute__((address_space(3))) void*)l, 16, 0, 0);
}

// ---------------------------------------------------------------------------
// Fused prep: [0,3072) conv_x | [3072,3504) tconv Wq | [3504,3648) tconv Wp
// ---------------------------------------------------------------------------
__global__ __launch_bounds__(256) void prep_all(const float* __restrict__ x,
                                                const float* __restrict__ wq,
                                                const float* __restrict__ wp,
                                                unsigned short* __restrict__ xb,
                                                unsigned short* __restrict__ wqt,
                                                unsigned short* __restrict__ wpt) {
    __shared__ unsigned short tile[64][68];
    const int bid = blockIdx.x;
    const int t = threadIdx.x;

    if (bid < 3072) {                       // ---- conv_x: one us8 per thread
        const size_t i8 = (size_t)bid * 256 + t;   // < 786432 exactly
        f32x4 a = *(const f32x4*)&x[i8 * 8];
        f32x4 b = *(const f32x4*)&x[i8 * 8 + 4];
        us8 o;
#pragma unroll
        for (int j = 0; j < 4; ++j) { o[j] = f2bf(a[j]); o[4 + j] = f2bf(b[j]); }
        *(us8*)&xb[i8 * 8] = o;
        return;
    }

    // ---- transpose-convert: in [R][C] fp32 -> out [C][R] bf16, 64x64 tiles
    const float* in; unsigned short* out; int R, C, bx, by;
    if (bid < 3504) {
        const int bb = bid - 3072;          // 0..431 : Wq (768 x 2304)
        in = wq; out = wqt; R = CDIM; C = QKV_N;
        bx = (bb % 36) * 64; by = (bb / 36) * 64;
    } else {
        const int bb = bid - 3504;          // 0..143 : Wp (768 x 768)
        in = wp; out = wpt; R = CDIM; C = CDIM;
        bx = (bb % 12) * 64; by = (bb / 12) * 64;
    }
    const int rr = t >> 4;
    const int c4 = (t & 15) * 4;
#pragma unroll
    for (int i = 0; i < 4; ++i) {
        const int r = rr + i * 16;
        f32x4 v = *(const f32x4*)&in[(size_t)(by + r) * C + bx + c4];
#pragma unroll
        for (int j = 0; j < 4; ++j) tile[c4 + j][r] = f2bf(v[j]);
    }
    __syncthreads();
#pragma unroll
    for (int i = 0; i < 4; ++i) {
        const int r = rr + i * 16;
        us4 o;
#pragma unroll
        for (int j = 0; j < 4; ++j) o[j] = tile[r][c4 + j];
        *(us4*)&out[(size_t)(bx + r) * R + by + c4] = o;
    }
}

// ---------------------------------------------------------------------------
// GEMM1 (m97 structure, XCD swizzle: m on blockIdx.x) — unchanged from R34.
// ---------------------------------------------------------------------------
__global__ __launch_bounds__(256) void qkv_gemm2(const unsigned short* __restrict__ A,
                                                 const unsigned short* __restrict__ BT,
                                                 unsigned short* __restrict__ qkv) {
    __shared__ unsigned short a_lds[128][32];
    __shared__ unsigned short b_lds[128][32];
    const int m0 = blockIdx.x * 128;
    const int n0 = blockIdx.y * 128;
    const int t = threadIdx.x, lane = t & 63, w = t >> 6;
    const int wm = w >> 1, wn = w & 1;
    const int lr = lane & 15, kg = lane >> 4;
    const int srow = w * 16 + (lane >> 2);
    const int scol = (lane & 3) * 8;

    f32x4 acc[4][4];
#pragma unroll
    for (int i = 0; i < 4; ++i)
#pragma unroll
        for (int j = 0; j < 4; ++j) acc[i][j] = (f32x4)0.f;

    unsigned short* ab0 = &a_lds[0][0] + w * 512;
    unsigned short* ab1 = &a_lds[0][0] + (4 + w) * 512;
    unsigned short* bb0 = &b_lds[0][0] + w * 512;
    unsigned short* bb1 = &b_lds[0][0] + (4 + w) * 512;

    for (int kt = 0; kt < 24; ++kt) {
        const int k0 = kt * 32;
        __syncthreads();
        gl_lds16(&A[(size_t)(m0 + srow) * CDIM + k0 + scol], ab0);
        gl_lds16(&A[(size_t)(m0 + 64 + srow) * CDIM + k0 + scol], ab1);
        gl_lds16(&BT[(size_t)(n0 + srow) * CDIM + k0 + scol], bb0);
        gl_lds16(&BT[(size_t)(n0 + 64 + srow) * CDIM + k0 + scol], bb1);
        __syncthreads();

        bf16x8 afr[4], bfr[4];
#pragma unroll
        for (int i = 0; i < 4; ++i)
            afr[i] = *(const bf16x8*)&a_lds[wm * 64 + i * 16 + lr][kg * 8];
#pragma unroll
        for (int j = 0; j < 4; ++j)
            bfr[j] = *(const bf16x8*)&b_lds[wn * 64 + j * 16 + lr][kg * 8];
#pragma unroll
        for (int i = 0; i < 4; ++i)
#pragma unroll
            for (int j = 0; j < 4; ++j)
                acc[i][j] = __builtin_amdgcn_mfma_f32_16x16x32_bf16(afr[i], bfr[j],
                                                                    acc[i][j], 0, 0, 0);
    }

#pragma unroll
    for (int j = 0; j < 4; ++j) {
        const int c = n0 + wn * 64 + j * 16 + lr;
        const int three = (c >= 1536) ? 2 : ((c >= 768) ? 1 : 0);
        const int rem = c - three * 768;
        const int h = rem >> 6, d = rem & 63;
        const float mul = (three == 0) ? 0.125f : 1.0f;
#pragma unroll
        for (int i = 0; i < 4; ++i) {
#pragma unroll
            for (int rg = 0; rg < 4; ++rg) {
                const int m = m0 + wm * 64 + i * 16 + kg * 4 + rg;
                const int bb = m >> 10, n = m & 1023;
                qkv[(size_t)three * BHND +
                    ((size_t)(bb * NHEADS + h) * SEQ + n) * HDIM + d] =
                    f2bf(acc[i][j][rg] * mul);
            }
        }
    }
}

// ---------------------------------------------------------------------------
// Flash attention v7c = v7b + EXACT defer-max: when the running max does not
// grow (mnew == m_old), corr == 1 exactly, so the rescale is an identity —
// skip it (wave-uniform branch via __any). Bit-identical numerics.
// ---------------------------------------------------------------------------
__global__ __launch_bounds__(256) void attn_kernel7c(const unsigned short* __restrict__ qkv,
                                                     unsigned short* __restrict__ aout) {
    __shared__ unsigned short v_lds[2][64][72];      // [buf][d][key]
    __shared__ unsigned short p_lds[4][2][16][72];   // [wave][tile][q][k]
    const int bh = blockIdx.x;                       // 0..95  (XCD = bh%8)
    const int qt = blockIdx.y;                       // 0..7
    const int t = threadIdx.x, lane = t & 63, w = t >> 6;
    const int lr = lane & 15, kg = lane >> 4;
    const unsigned short* Q = qkv + (size_t)bh * SEQ * HDIM;
    const unsigned short* K = qkv + BHND + (size_t)bh * SEQ * HDIM;
    const unsigned short* V = qkv + 2 * BHND + (size_t)bh * SEQ * HDIM;

    const int qA = qt * 128 + w * 32;
    bf16x8 qfA[2], qfB[2];
#pragma unroll
    for (int ks = 0; ks < 2; ++ks) {
        qfA[ks] = *(const bf16x8*)&Q[(size_t)(qA + lr) * HDIM + ks * 32 + kg * 8];
        qfB[ks] = *(const bf16x8*)&Q[(size_t)(qA + 16 + lr) * HDIM + ks * 32 + kg * 8];
    }

    const int skey = t >> 4, sd4 = (t & 15) * 4;
#pragma unroll
    for (int i = 0; i < 4; ++i) {
        const int key = skey + i * 16;
        us4 vvv = *(const us4*)&V[(size_t)key * HDIM + sd4];
#pragma unroll
        for (int j = 0; j < 4; ++j) v_lds[0][sd4 + j][key] = vvv[j];
    }
    __syncthreads();

    float mA = -1e30f, lA = 0.f, mB = -1e30f, lB = 0.f;
    f32x4 oaccA[4], oaccB[4];
#pragma unroll
    for (int jd = 0; jd < 4; ++jd) { oaccA[jd] = (f32x4)0.f; oaccB[jd] = (f32x4)0.f; }

    for (int kv = 0; kv < 16; ++kv) {
        const int kb = kv * 64;
        if (kv < 15) {
            const int buf = (kv + 1) & 1;
#pragma unroll
            for (int i = 0; i < 4; ++i) {
                const int key = skey + i * 16;
                us4 vvv = *(const us4*)&V[(size_t)(kb + 64 + key) * HDIM + sd4];
#pragma unroll
                for (int j = 0; j < 4; ++j) v_lds[buf][sd4 + j][key] = vvv[j];
            }
        }

        // S^T[k][q] = K·Q^T (K direct from XCD-resident L2)
        f32x4 sA[4], sB[4];
        __builtin_amdgcn_s_setprio(1);
#pragma unroll
        for (int jj = 0; jj < 4; ++jj) {
            sA[jj] = (f32x4)0.f; sB[jj] = (f32x4)0.f;
#pragma unroll
            for (int ks = 0; ks < 2; ++ks) {
                bf16x8 kf = *(const bf16x8*)&K[(size_t)(kb + jj * 16 + lr) * HDIM + ks * 32 + kg * 8];
                sA[jj] = __builtin_amdgcn_mfma_f32_16x16x32_bf16(kf, qfA[ks], sA[jj], 0, 0, 0);
                sB[jj] = __builtin_amdgcn_mfma_f32_16x16x32_bf16(kf, qfB[ks], sB[jj], 0, 0, 0);
            }
        }
        __builtin_amdgcn_s_setprio(0);

        // ---- tile A: max + exp + P-write; rescale deferred (exact skip) ----
        bool growA, growB;
        float corrA = 1.f, corrB = 1.f;
        {
            float m0 = fmaxf(fmaxf(sA[0][0], sA[0][1]), fmaxf(sA[0][2], sA[0][3]));
            float m1 = fmaxf(fmaxf(sA[1][0], sA[1][1]), fmaxf(sA[1][2], sA[1][3]));
            float m2 = fmaxf(fmaxf(sA[2][0], sA[2][1]), fmaxf(sA[2][2], sA[2][3]));
            float m3 = fmaxf(fmaxf(sA[3][0], sA[3][1]), fmaxf(sA[3][2], sA[3][3]));
            float mx = fmaxf(fmaxf(m0, m1), fmaxf(m2, m3));
            mx = fmaxf(mx, __shfl_xor(mx, 16, 64));
            mx = fmaxf(mx, __shfl_xor(mx, 32, 64));
            growA = __any(mx > mA);
            const float mnew = growA ? fmaxf(mA, mx) : mA;
            float rs = 0.f;
#pragma unroll
            for (int jj = 0; jj < 4; ++jj)
#pragma unroll
                for (int r = 0; r < 4; ++r) { sA[jj][r] = __expf(sA[jj][r] - mnew); rs += sA[jj][r]; }
#pragma unroll
            for (int jj = 0; jj < 4; ++jj)
#pragma unroll
                for (int r = 0; r < 4; ++r)
                    p_lds[w][0][lr][jj * 16 + kg * 4 + r] = f2bf(sA[jj][r]);
            rs += __shfl_xor(rs, 16, 64);
            rs += __shfl_xor(rs, 32, 64);
            if (growA) { corrA = __expf(mA - mnew); lA = lA * corrA + rs; mA = mnew; }
            else       { lA += rs; }
        }
        {
            float m0 = fmaxf(fmaxf(sB[0][0], sB[0][1]), fmaxf(sB[0][2], sB[0][3]));
            float m1 = fmaxf(fmaxf(sB[1][0], sB[1][1]), fmaxf(sB[1][2], sB[1][3]));
            float m2 = fmaxf(fmaxf(sB[2][0], sB[2][1]), fmaxf(sB[2][2], sB[2][3]));
            float m3 = fmaxf(fmaxf(sB[3][0], sB[3][1]), fmaxf(sB[3][2], sB[3][3]));
            float mx = fmaxf(fmaxf(m0, m1), fmaxf(m2, m3));
            mx = fmaxf(mx, __shfl_xor(mx, 16, 64));
            mx = fmaxf(mx, __shfl_xor(mx, 32, 64));
            growB = __any(mx > mB);
            const float mnew = growB ? fmaxf(mB, mx) : mB;
            float rs = 0.f;
#pragma unroll
            for (int jj = 0; jj < 4; ++jj)
#pragma unroll
                for (int r = 0; r < 4; ++r) { sB[jj][r] = __expf(sB[jj][r] - mnew); rs += sB[jj][r]; }
#pragma unroll
            for (int jj = 0; jj < 4; ++jj)
#pragma unroll
                for (int r = 0; r < 4; ++r)
                    p_lds[w][1][lr][jj * 16 + kg * 4 + r] = f2bf(sB[jj][r]);
            rs += __shfl_xor(rs, 16, 64);
            rs += __shfl_xor(rs, 32, 64);
            if (growB) { corrB = __expf(mB - mnew); lB = lB * corrB + rs; mB = mnew; }
            else       { lB += rs; }
        }
        // rescale only when the max grew (corr==1 identity otherwise)
        if (growA) {
#pragma unroll
            for (int jd = 0; jd < 4; ++jd)
#pragma unroll
                for (int r = 0; r < 4; ++r) oaccA[jd][r] *= corrA;
        }
        if (growB) {
#pragma unroll
            for (int jd = 0; jd < 4; ++jd)
#pragma unroll
                for (int r = 0; r < 4; ++r) oaccB[jd][r] *= corrB;
        }

        asm volatile("s_waitcnt lgkmcnt(0)" ::: "memory");
        __builtin_amdgcn_sched_barrier(0);

        // O^T += V^T · P^T
        const int cb = kv & 1;
        __builtin_amdgcn_s_setprio(1);
#pragma unroll
        for (int c = 0; c < 2; ++c) {
            bf16x8 pfA = *(const bf16x8*)&p_lds[w][0][lr][c * 32 + kg * 8];
            bf16x8 pfB = *(const bf16x8*)&p_lds[w][1][lr][c * 32 + kg * 8];
#pragma unroll
            for (int jd = 0; jd < 4; ++jd) {
                bf16x8 vf = *(const bf16x8*)&v_lds[cb][jd * 16 + lr][c * 32 + kg * 8];
                oaccA[jd] = __builtin_amdgcn_mfma_f32_16x16x32_bf16(vf, pfA, oaccA[jd], 0, 0, 0);
                oaccB[jd] = __builtin_amdgcn_mfma_f32_16x16x32_bf16(vf, pfB, oaccB[jd], 0, 0, 0);
            }
        }
        __builtin_amdgcn_s_setprio(0);

        __syncthreads();
    }

    const int bb = bh / NHEADS, h = bh % NHEADS;
    const float invA = 1.0f / lA, invB = 1.0f / lB;
#pragma unroll
    for (int jd = 0; jd < 4; ++jd) {
#pragma unroll
        for (int r = 0; r < 4; ++r) {
            const int d = jd * 16 + kg * 4 + r;
            aout[((size_t)(bb * SEQ + qA + lr)) * CDIM + h * HDIM + d] =
                f2bf(oaccA[jd][r] * invA);
            aout[((size_t)(bb * SEQ + qA + 16 + lr)) * CDIM + h * HDIM + d] =
                f2bf(oaccB[jd][r] * invB);
        }
    }
}

// ---------------------------------------------------------------------------
// GEMM2 (m97 structure, XCD swizzle) — unchanged from R34.
// ---------------------------------------------------------------------------
__global__ __launch_bounds__(256) void proj_gemm2(const unsigned short* __restrict__ A,
                                                  const unsigned short* __restrict__ BT,
                                                  float* __restrict__ out) {
    __shared__ unsigned short a_lds[128][32];
    __shared__ unsigned short b_lds[128][32];
    const int m0 = blockIdx.x * 128;
    const int n0 = blockIdx.y * 128;
    const int t = threadIdx.x, lane = t & 63, w = t >> 6;
    const int wm = w >> 1, wn = w & 1;
    const int lr = lane & 15, kg = lane >> 4;
    const int srow = w * 16 + (lane >> 2);
    const int scol = (lane & 3) * 8;

    f32x4 acc[4][4];
#pragma unroll
    for (int i = 0; i < 4; ++i)
#pragma unroll
        for (int j = 0; j < 4; ++j) acc[i][j] = (f32x4)0.f;

    unsigned short* ab0 = &a_lds[0][0] + w * 512;
    unsigned short* ab1 = &a_lds[0][0] + (4 + w) * 512;
    unsigned short* bb0 = &b_lds[0][0] + w * 512;
    unsigned short* bb1 = &b_lds[0][0] + (4 + w) * 512;

    for (int kt = 0; kt < 24; ++kt) {
        const int k0 = kt * 32;
        __syncthreads();
        gl_lds16(&A[(size_t)(m0 + srow) * CDIM + k0 + scol], ab0);
        gl_lds16(&A[(size_t)(m0 + 64 + srow) * CDIM + k0 + scol], ab1);
        gl_lds16(&BT[(size_t)(n0 + srow) * CDIM + k0 + scol], bb0);
        gl_lds16(&BT[(size_t)(n0 + 64 + srow) * CDIM + k0 + scol], bb1);
        __syncthreads();

        bf16x8 afr[4], bfr[4];
#pragma unroll
        for (int i = 0; i < 4; ++i)
            afr[i] = *(const bf16x8*)&a_lds[wm * 64 + i * 16 + lr][kg * 8];
#pragma unroll
        for (int j = 0; j < 4; ++j)
            bfr[j] = *(const bf16x8*)&b_lds[wn * 64 + j * 16 + lr][kg * 8];
#pragma unroll
        for (int i = 0; i < 4; ++i)
#pragma unroll
            for (int j = 0; j < 4; ++j)
                acc[i][j] = __builtin_amdgcn_mfma_f32_16x16x32_bf16(afr[i], bfr[j],
                                                                    acc[i][j], 0, 0, 0);
    }

#pragma unroll
    for (int i = 0; i < 4; ++i)
#pragma unroll
        for (int j = 0; j < 4; ++j)
#pragma unroll
            for (int rg = 0; rg < 4; ++rg) {
                const int m = m0 + wm * 64 + i * 16 + kg * 4 + rg;
                const int c = n0 + wn * 64 + j * 16 + lr;
                out[(size_t)m * CDIM + c] = acc[i][j][rg];
            }
}

// ---------------------------------------------------------------------------
extern "C" void kernel_launch(void* const* d_in, const int* in_sizes, int n_in,
                              void* d_out, int out_size, void* d_ws, size_t ws_size,
                              hipStream_t stream) {
    const float* x      = (const float*)d_in[0];
    const float* w_qkv  = (const float*)d_in[1];
    const float* w_proj = (const float*)d_in[2];

    unsigned short* qkv  = (unsigned short*)d_ws;
    unsigned short* aout = qkv + 3 * BHND;
    unsigned short* xb   = aout + NX;
    unsigned short* wqt  = xb + NX;
    unsigned short* wpt  = wqt + NWQ;
    float* out = (float*)d_out;

    prep_all<<<3648, 256, 0, stream>>>(x, w_qkv, w_proj, xb, wqt, wpt);
    qkv_gemm2<<<dim3(64, 18), 256, 0, stream>>>(xb, wqt, qkv);
    attn_kernel7c<<<dim3(96, 8), 256, 0, stream>>>(qkv, aout);
    proj_gemm2<<<dim3(64, 6), 256, 0, stream>>>(aout, wpt, out);
}

// Round 36
// 151.778 us; speedup vs baseline: 1.1645x; 1.1645x over previous
//
#include <hip/hip_runtime.h>
#include <cstdint>
#include <cstddef>

typedef __attribute__((ext_vector_type(8))) short bf16x8;
typedef __attribute__((ext_vector_type(4))) float f32x4;
typedef __attribute__((ext_vector_type(4))) unsigned short us4;
typedef __attribute__((ext_vector_type(8))) unsigned short us8;

#define NHEADS 12
#define BATCH 8
#define SEQ 1024
#define HDIM 64
#define CDIM 768
#define QKV_N 2304
#define BHND ((size_t)(BATCH) * NHEADS * SEQ * HDIM)   // 6291456
#define NX   ((size_t)8192 * 768)                      // 6291456
#define NWQ  ((size_t)768 * 2304)                      // 1769472
#define NWP  ((size_t)768 * 768)                       // 589824

__device__ __forceinline__ unsigned short f2bf(float f) {
    union { float f; uint32_t u; } v; v.f = f;
    uint32_t u = v.u;
    u += 0x7fffu + ((u >> 16) & 1u);   // RNE
    return (unsigned short)(u >> 16);
}

__device__ __forceinline__ void gl_lds16(const unsigned short* g, unsigned short* l) {
    __builtin_amdgcn_global_load_lds(
        (const __attribute__((address_space(1))) void*)g,
        (__attribute__((address_space(3))) void*)l, 16, 0, 0);
}

// ---------------------------------------------------------------------------
// Fused prep: [0,3072) conv_x | [3072,3504) tconv Wq | [3504,3648) tconv Wp
// ---------------------------------------------------------------------------
__global__ __launch_bounds__(256) void prep_all(const float* __restrict__ x,
                                                const float* __restrict__ wq,
                                                const float* __restrict__ wp,
                                                unsigned short* __restrict__ xb,
                                                unsigned short* __restrict__ wqt,
                                                unsigned short* __restrict__ wpt) {
    __shared__ unsigned short tile[64][68];
    const int bid = blockIdx.x;
    const int t = threadIdx.x;

    if (bid < 3072) {                       // ---- conv_x: one us8 per thread
        const size_t i8 = (size_t)bid * 256 + t;   // < 786432 exactly
        f32x4 a = *(const f32x4*)&x[i8 * 8];
        f32x4 b = *(const f32x4*)&x[i8 * 8 + 4];
        us8 o;
#pragma unroll
        for (int j = 0; j < 4; ++j) { o[j] = f2bf(a[j]); o[4 + j] = f2bf(b[j]); }
        *(us8*)&xb[i8 * 8] = o;
        return;
    }

    // ---- transpose-convert: in [R][C] fp32 -> out [C][R] bf16, 64x64 tiles
    const float* in; unsigned short* out; int R, C, bx, by;
    if (bid < 3504) {
        const int bb = bid - 3072;          // 0..431 : Wq (768 x 2304)
        in = wq; out = wqt; R = CDIM; C = QKV_N;
        bx = (bb % 36) * 64; by = (bb / 36) * 64;
    } else {
        const int bb = bid - 3504;          // 0..143 : Wp (768 x 768)
        in = wp; out = wpt; R = CDIM; C = CDIM;
        bx = (bb % 12) * 64; by = (bb / 12) * 64;
    }
    const int rr = t >> 4;
    const int c4 = (t & 15) * 4;
#pragma unroll
    for (int i = 0; i < 4; ++i) {
        const int r = rr + i * 16;
        f32x4 v = *(const f32x4*)&in[(size_t)(by + r) * C + bx + c4];
#pragma unroll
        for (int j = 0; j < 4; ++j) tile[c4 + j][r] = f2bf(v[j]);
    }
    __syncthreads();
#pragma unroll
    for (int i = 0; i < 4; ++i) {
        const int r = rr + i * 16;
        us4 o;
#pragma unroll
        for (int j = 0; j < 4; ++j) o[j] = tile[r][c4 + j];
        *(us4*)&out[(size_t)(bx + r) * R + by + c4] = o;
    }
}

// ---------------------------------------------------------------------------
// GEMM1 (m97 structure, XCD swizzle: m on blockIdx.x) — R34-proven.
// ---------------------------------------------------------------------------
__global__ __launch_bounds__(256) void qkv_gemm2(const unsigned short* __restrict__ A,
                                                 const unsigned short* __restrict__ BT,
                                                 unsigned short* __restrict__ qkv) {
    __shared__ unsigned short a_lds[128][32];
    __shared__ unsigned short b_lds[128][32];
    const int m0 = blockIdx.x * 128;
    const int n0 = blockIdx.y * 128;
    const int t = threadIdx.x, lane = t & 63, w = t >> 6;
    const int wm = w >> 1, wn = w & 1;
    const int lr = lane & 15, kg = lane >> 4;
    const int srow = w * 16 + (lane >> 2);
    const int scol = (lane & 3) * 8;

    f32x4 acc[4][4];
#pragma unroll
    for (int i = 0; i < 4; ++i)
#pragma unroll
        for (int j = 0; j < 4; ++j) acc[i][j] = (f32x4)0.f;

    unsigned short* ab0 = &a_lds[0][0] + w * 512;
    unsigned short* ab1 = &a_lds[0][0] + (4 + w) * 512;
    unsigned short* bb0 = &b_lds[0][0] + w * 512;
    unsigned short* bb1 = &b_lds[0][0] + (4 + w) * 512;

    for (int kt = 0; kt < 24; ++kt) {
        const int k0 = kt * 32;
        __syncthreads();
        gl_lds16(&A[(size_t)(m0 + srow) * CDIM + k0 + scol], ab0);
        gl_lds16(&A[(size_t)(m0 + 64 + srow) * CDIM + k0 + scol], ab1);
        gl_lds16(&BT[(size_t)(n0 + srow) * CDIM + k0 + scol], bb0);
        gl_lds16(&BT[(size_t)(n0 + 64 + srow) * CDIM + k0 + scol], bb1);
        __syncthreads();

        bf16x8 afr[4], bfr[4];
#pragma unroll
        for (int i = 0; i < 4; ++i)
            afr[i] = *(const bf16x8*)&a_lds[wm * 64 + i * 16 + lr][kg * 8];
#pragma unroll
        for (int j = 0; j < 4; ++j)
            bfr[j] = *(const bf16x8*)&b_lds[wn * 64 + j * 16 + lr][kg * 8];
#pragma unroll
        for (int i = 0; i < 4; ++i)
#pragma unroll
            for (int j = 0; j < 4; ++j)
                acc[i][j] = __builtin_amdgcn_mfma_f32_16x16x32_bf16(afr[i], bfr[j],
                                                                    acc[i][j], 0, 0, 0);
    }

#pragma unroll
    for (int j = 0; j < 4; ++j) {
        const int c = n0 + wn * 64 + j * 16 + lr;
        const int three = (c >= 1536) ? 2 : ((c >= 768) ? 1 : 0);
        const int rem = c - three * 768;
        const int h = rem >> 6, d = rem & 63;
        const float mul = (three == 0) ? 0.125f : 1.0f;
#pragma unroll
        for (int i = 0; i < 4; ++i) {
#pragma unroll
            for (int rg = 0; rg < 4; ++rg) {
                const int m = m0 + wm * 64 + i * 16 + kg * 4 + rg;
                const int bb = m >> 10, n = m & 1023;
                qkv[(size_t)three * BHND +
                    ((size_t)(bb * NHEADS + h) * SEQ + n) * HDIM + d] =
                    f2bf(acc[i][j][rg] * mul);
            }
        }
    }
}

// ---------------------------------------------------------------------------
// Flash attention v7b — EXACT R34 kernel (measured 86.0us, VGPR 76).
// ---------------------------------------------------------------------------
__global__ __launch_bounds__(256) void attn_kernel7b(const unsigned short* __restrict__ qkv,
                                                     unsigned short* __restrict__ aout) {
    __shared__ unsigned short v_lds[2][64][72];      // [buf][d][key]
    __shared__ unsigned short p_lds[4][2][16][72];   // [wave][tile][q][k]
    const int bh = blockIdx.x;                       // 0..95  (XCD = bh%8)
    const int qt = blockIdx.y;                       // 0..7
    const int t = threadIdx.x, lane = t & 63, w = t >> 6;
    const int lr = lane & 15, kg = lane >> 4;
    const unsigned short* Q = qkv + (size_t)bh * SEQ * HDIM;
    const unsigned short* K = qkv + BHND + (size_t)bh * SEQ * HDIM;
    const unsigned short* V = qkv + 2 * BHND + (size_t)bh * SEQ * HDIM;

    const int qA = qt * 128 + w * 32;
    bf16x8 qfA[2], qfB[2];
#pragma unroll
    for (int ks = 0; ks < 2; ++ks) {
        qfA[ks] = *(const bf16x8*)&Q[(size_t)(qA + lr) * HDIM + ks * 32 + kg * 8];
        qfB[ks] = *(const bf16x8*)&Q[(size_t)(qA + 16 + lr) * HDIM + ks * 32 + kg * 8];
    }

    const int skey = t >> 4, sd4 = (t & 15) * 4;
#pragma unroll
    for (int i = 0; i < 4; ++i) {
        const int key = skey + i * 16;
        us4 vvv = *(const us4*)&V[(size_t)key * HDIM + sd4];
#pragma unroll
        for (int j = 0; j < 4; ++j) v_lds[0][sd4 + j][key] = vvv[j];
    }
    __syncthreads();

    float mA = -1e30f, lA = 0.f, mB = -1e30f, lB = 0.f;
    f32x4 oaccA[4], oaccB[4];
#pragma unroll
    for (int jd = 0; jd < 4; ++jd) { oaccA[jd] = (f32x4)0.f; oaccB[jd] = (f32x4)0.f; }

    for (int kv = 0; kv < 16; ++kv) {
        const int kb = kv * 64;
        if (kv < 15) {
            const int buf = (kv + 1) & 1;
#pragma unroll
            for (int i = 0; i < 4; ++i) {
                const int key = skey + i * 16;
                us4 vvv = *(const us4*)&V[(size_t)(kb + 64 + key) * HDIM + sd4];
#pragma unroll
                for (int j = 0; j < 4; ++j) v_lds[buf][sd4 + j][key] = vvv[j];
            }
        }

        // S^T[k][q] = K·Q^T (K direct from XCD-resident L2)
        f32x4 sA[4], sB[4];
        __builtin_amdgcn_s_setprio(1);
#pragma unroll
        for (int jj = 0; jj < 4; ++jj) {
            sA[jj] = (f32x4)0.f; sB[jj] = (f32x4)0.f;
#pragma unroll
            for (int ks = 0; ks < 2; ++ks) {
                bf16x8 kf = *(const bf16x8*)&K[(size_t)(kb + jj * 16 + lr) * HDIM + ks * 32 + kg * 8];
                sA[jj] = __builtin_amdgcn_mfma_f32_16x16x32_bf16(kf, qfA[ks], sA[jj], 0, 0, 0);
                sB[jj] = __builtin_amdgcn_mfma_f32_16x16x32_bf16(kf, qfB[ks], sB[jj], 0, 0, 0);
            }
        }
        __builtin_amdgcn_s_setprio(0);

        // ---- tile A: max + exp + P-write, then rescale (hides ds_writes) ----
        float corrA, corrB;
        {
            float m0 = fmaxf(fmaxf(sA[0][0], sA[0][1]), fmaxf(sA[0][2], sA[0][3]));
            float m1 = fmaxf(fmaxf(sA[1][0], sA[1][1]), fmaxf(sA[1][2], sA[1][3]));
            float m2 = fmaxf(fmaxf(sA[2][0], sA[2][1]), fmaxf(sA[2][2], sA[2][3]));
            float m3 = fmaxf(fmaxf(sA[3][0], sA[3][1]), fmaxf(sA[3][2], sA[3][3]));
            float mx = fmaxf(fmaxf(m0, m1), fmaxf(m2, m3));
            mx = fmaxf(mx, __shfl_xor(mx, 16, 64));
            mx = fmaxf(mx, __shfl_xor(mx, 32, 64));
            const float mnew = fmaxf(mA, mx);
            corrA = __expf(mA - mnew);
            float rs = 0.f;
#pragma unroll
            for (int jj = 0; jj < 4; ++jj)
#pragma unroll
                for (int r = 0; r < 4; ++r) { sA[jj][r] = __expf(sA[jj][r] - mnew); rs += sA[jj][r]; }
#pragma unroll
            for (int jj = 0; jj < 4; ++jj)
#pragma unroll
                for (int r = 0; r < 4; ++r)
                    p_lds[w][0][lr][jj * 16 + kg * 4 + r] = f2bf(sA[jj][r]);
            rs += __shfl_xor(rs, 16, 64);
            rs += __shfl_xor(rs, 32, 64);
            lA = lA * corrA + rs; mA = mnew;
        }
        {
            float m0 = fmaxf(fmaxf(sB[0][0], sB[0][1]), fmaxf(sB[0][2], sB[0][3]));
            float m1 = fmaxf(fmaxf(sB[1][0], sB[1][1]), fmaxf(sB[1][2], sB[1][3]));
            float m2 = fmaxf(fmaxf(sB[2][0], sB[2][1]), fmaxf(sB[2][2], sB[2][3]));
            float m3 = fmaxf(fmaxf(sB[3][0], sB[3][1]), fmaxf(sB[3][2], sB[3][3]));
            float mx = fmaxf(fmaxf(m0, m1), fmaxf(m2, m3));
            mx = fmaxf(mx, __shfl_xor(mx, 16, 64));
            mx = fmaxf(mx, __shfl_xor(mx, 32, 64));
            const float mnew = fmaxf(mB, mx);
            corrB = __expf(mB - mnew);
            float rs = 0.f;
#pragma unroll
            for (int jj = 0; jj < 4; ++jj)
#pragma unroll
                for (int r = 0; r < 4; ++r) { sB[jj][r] = __expf(sB[jj][r] - mnew); rs += sB[jj][r]; }
#pragma unroll
            for (int jj = 0; jj < 4; ++jj)
#pragma unroll
                for (int r = 0; r < 4; ++r)
                    p_lds[w][1][lr][jj * 16 + kg * 4 + r] = f2bf(sB[jj][r]);
            rs += __shfl_xor(rs, 16, 64);
            rs += __shfl_xor(rs, 32, 64);
            lB = lB * corrB + rs; mB = mnew;
        }
        // rescale oacc while the ds_writes retire
#pragma unroll
        for (int jd = 0; jd < 4; ++jd)
#pragma unroll
            for (int r = 0; r < 4; ++r) { oaccA[jd][r] *= corrA; oaccB[jd][r] *= corrB; }

        asm volatile("s_waitcnt lgkmcnt(0)" ::: "memory");
        __builtin_amdgcn_sched_barrier(0);

        // O^T += V^T · P^T
        const int cb = kv & 1;
        __builtin_amdgcn_s_setprio(1);
#pragma unroll
        for (int c = 0; c < 2; ++c) {
            bf16x8 pfA = *(const bf16x8*)&p_lds[w][0][lr][c * 32 + kg * 8];
            bf16x8 pfB = *(const bf16x8*)&p_lds[w][1][lr][c * 32 + kg * 8];
#pragma unroll
            for (int jd = 0; jd < 4; ++jd) {
                bf16x8 vf = *(const bf16x8*)&v_lds[cb][jd * 16 + lr][c * 32 + kg * 8];
                oaccA[jd] = __builtin_amdgcn_mfma_f32_16x16x32_bf16(vf, pfA, oaccA[jd], 0, 0, 0);
                oaccB[jd] = __builtin_amdgcn_mfma_f32_16x16x32_bf16(vf, pfB, oaccB[jd], 0, 0, 0);
            }
        }
        __builtin_amdgcn_s_setprio(0);

        __syncthreads();
    }

    const int bb = bh / NHEADS, h = bh % NHEADS;
    const float invA = 1.0f / lA, invB = 1.0f / lB;
#pragma unroll
    for (int jd = 0; jd < 4; ++jd) {
#pragma unroll
        for (int r = 0; r < 4; ++r) {
            const int d = jd * 16 + kg * 4 + r;
            aout[((size_t)(bb * SEQ + qA + lr)) * CDIM + h * HDIM + d] =
                f2bf(oaccA[jd][r] * invA);
            aout[((size_t)(bb * SEQ + qA + 16 + lr)) * CDIM + h * HDIM + d] =
                f2bf(oaccB[jd][r] * invB);
        }
    }
}

// ---------------------------------------------------------------------------
// GEMM2 (m97 structure, XCD swizzle) — R34-proven.
// ---------------------------------------------------------------------------
__global__ __launch_bounds__(256) void proj_gemm2(const unsigned short* __restrict__ A,
                                                  const unsigned short* __restrict__ BT,
                                                  float* __restrict__ out) {
    __shared__ unsigned short a_lds[128][32];
    __shared__ unsigned short b_lds[128][32];
    const int m0 = blockIdx.x * 128;
    const int n0 = blockIdx.y * 128;
    const int t = threadIdx.x, lane = t & 63, w = t >> 6;
    const int wm = w >> 1, wn = w & 1;
    const int lr = lane & 15, kg = lane >> 4;
    const int srow = w * 16 + (lane >> 2);
    const int scol = (lane & 3) * 8;

    f32x4 acc[4][4];
#pragma unroll
    for (int i = 0; i < 4; ++i)
#pragma unroll
        for (int j = 0; j < 4; ++j) acc[i][j] = (f32x4)0.f;

    unsigned short* ab0 = &a_lds[0][0] + w * 512;
    unsigned short* ab1 = &a_lds[0][0] + (4 + w) * 512;
    unsigned short* bb0 = &b_lds[0][0] + w * 512;
    unsigned short* bb1 = &b_lds[0][0] + (4 + w) * 512;

    for (int kt = 0; kt < 24; ++kt) {
        const int k0 = kt * 32;
        __syncthreads();
        gl_lds16(&A[(size_t)(m0 + srow) * CDIM + k0 + scol], ab0);
        gl_lds16(&A[(size_t)(m0 + 64 + srow) * CDIM + k0 + scol], ab1);
        gl_lds16(&BT[(size_t)(n0 + srow) * CDIM + k0 + scol], bb0);
        gl_lds16(&BT[(size_t)(n0 + 64 + srow) * CDIM + k0 + scol], bb1);
        __syncthreads();

        bf16x8 afr[4], bfr[4];
#pragma unroll
        for (int i = 0; i < 4; ++i)
            afr[i] = *(const bf16x8*)&a_lds[wm * 64 + i * 16 + lr][kg * 8];
#pragma unroll
        for (int j = 0; j < 4; ++j)
            bfr[j] = *(const bf16x8*)&b_lds[wn * 64 + j * 16 + lr][kg * 8];
#pragma unroll
        for (int i = 0; i < 4; ++i)
#pragma unroll
            for (int j = 0; j < 4; ++j)
                acc[i][j] = __builtin_amdgcn_mfma_f32_16x16x32_bf16(afr[i], bfr[j],
                                                                    acc[i][j], 0, 0, 0);
    }

#pragma unroll
    for (int i = 0; i < 4; ++i)
#pragma unroll
        for (int j = 0; j < 4; ++j)
#pragma unroll
            for (int rg = 0; rg < 4; ++rg) {
                const int m = m0 + wm * 64 + i * 16 + kg * 4 + rg;
                const int c = n0 + wn * 64 + j * 16 + lr;
                out[(size_t)m * CDIM + c] = acc[i][j][rg];
            }
}

// ---------------------------------------------------------------------------
extern "C" void kernel_launch(void* const* d_in, const int* in_sizes, int n_in,
                              void* d_out, int out_size, void* d_ws, size_t ws_size,
                              hipStream_t stream) {
    const float* x      = (const float*)d_in[0];
    const float* w_qkv  = (const float*)d_in[1];
    const float* w_proj = (const float*)d_in[2];

    unsigned short* qkv  = (unsigned short*)d_ws;
    unsigned short* aout = qkv + 3 * BHND;
    unsigned short* xb   = aout + NX;
    unsigned short* wqt  = xb + NX;
    unsigned short* wpt  = wqt + NWQ;
    float* out = (float*)d_out;

    prep_all<<<3648, 256, 0, stream>>>(x, w_qkv, w_proj, xb, wqt, wpt);
    qkv_gemm2<<<dim3(64, 18), 256, 0, stream>>>(xb, wqt, qkv);
    attn_kernel7b<<<dim3(96, 8), 256, 0, stream>>>(qkv, aout);
    proj_gemm2<<<dim3(64, 6), 256, 0, stream>>>(aout, wpt, out);
}

// Round 37
// 147.442 us; speedup vs baseline: 1.1987x; 1.0294x over previous
//
#include <hip/hip_runtime.h>
#include <cstdint>
#include <cstddef>

typedef __attribute__((ext_vector_type(8))) short bf16x8;
typedef __attribute__((ext_vector_type(4))) float f32x4;
typedef __attribute__((ext_vector_type(4))) unsigned short us4;
typedef __attribute__((ext_vector_type(8))) unsigned short us8;

#define NHEADS 12
#define BATCH 8
#define SEQ 1024
#define HDIM 64
#define CDIM 768
#define QKV_N 2304
#define BHND ((size_t)(BATCH) * NHEADS * SEQ * HDIM)   // 6291456
#define NX   ((size_t)8192 * 768)                      // 6291456
#define NWQ  ((size_t)768 * 2304)                      // 1769472
#define NWP  ((size_t)768 * 768)                       // 589824

__device__ __forceinline__ unsigned short f2bf(float f) {
    union { float f; uint32_t u; } v; v.f = f;
    uint32_t u = v.u;
    u += 0x7fffu + ((u >> 16) & 1u);   // RNE
    return (unsigned short)(u >> 16);
}

__device__ __forceinline__ void gl_lds16(const unsigned short* g, unsigned short* l) {
    __builtin_amdgcn_global_load_lds(
        (const __attribute__((address_space(1))) void*)g,
        (__attribute__((address_space(3))) void*)l, 16, 0, 0);
}

// ---------------------------------------------------------------------------
// Fused prep: [0,3072) conv_x | [3072,3504) tconv Wq | [3504,3648) tconv Wp
// ---------------------------------------------------------------------------
__global__ __launch_bounds__(256) void prep_all(const float* __restrict__ x,
                                                const float* __restrict__ wq,
                                                const float* __restrict__ wp,
                                                unsigned short* __restrict__ xb,
                                                unsigned short* __restrict__ wqt,
                                                unsigned short* __restrict__ wpt) {
    __shared__ unsigned short tile[64][68];
    const int bid = blockIdx.x;
    const int t = threadIdx.x;

    if (bid < 3072) {                       // ---- conv_x: one us8 per thread
        const size_t i8 = (size_t)bid * 256 + t;   // < 786432 exactly
        f32x4 a = *(const f32x4*)&x[i8 * 8];
        f32x4 b = *(const f32x4*)&x[i8 * 8 + 4];
        us8 o;
#pragma unroll
        for (int j = 0; j < 4; ++j) { o[j] = f2bf(a[j]); o[4 + j] = f2bf(b[j]); }
        *(us8*)&xb[i8 * 8] = o;
        return;
    }

    // ---- transpose-convert: in [R][C] fp32 -> out [C][R] bf16, 64x64 tiles
    const float* in; unsigned short* out; int R, C, bx, by;
    if (bid < 3504) {
        const int bb = bid - 3072;          // 0..431 : Wq (768 x 2304)
        in = wq; out = wqt; R = CDIM; C = QKV_N;
        bx = (bb % 36) * 64; by = (bb / 36) * 64;
    } else {
        const int bb = bid - 3504;          // 0..143 : Wp (768 x 768)
        in = wp; out = wpt; R = CDIM; C = CDIM;
        bx = (bb % 12) * 64; by = (bb / 12) * 64;
    }
    const int rr = t >> 4;
    const int c4 = (t & 15) * 4;
#pragma unroll
    for (int i = 0; i < 4; ++i) {
        const int r = rr + i * 16;
        f32x4 v = *(const f32x4*)&in[(size_t)(by + r) * C + bx + c4];
#pragma unroll
        for (int j = 0; j < 4; ++j) tile[c4 + j][r] = f2bf(v[j]);
    }
    __syncthreads();
#pragma unroll
    for (int i = 0; i < 4; ++i) {
        const int r = rr + i * 16;
        us4 o;
#pragma unroll
        for (int j = 0; j < 4; ++j) o[j] = tile[r][c4 + j];
        *(us4*)&out[(size_t)(bx + r) * R + by + c4] = o;
    }
}

// ---------------------------------------------------------------------------
// GEMM1 (m97 structure, XCD swizzle: m on blockIdx.x) — R34-proven.
// ---------------------------------------------------------------------------
__global__ __launch_bounds__(256) void qkv_gemm2(const unsigned short* __restrict__ A,
                                                 const unsigned short* __restrict__ BT,
                                                 unsigned short* __restrict__ qkv) {
    __shared__ unsigned short a_lds[128][32];
    __shared__ unsigned short b_lds[128][32];
    const int m0 = blockIdx.x * 128;
    const int n0 = blockIdx.y * 128;
    const int t = threadIdx.x, lane = t & 63, w = t >> 6;
    const int wm = w >> 1, wn = w & 1;
    const int lr = lane & 15, kg = lane >> 4;
    const int srow = w * 16 + (lane >> 2);
    const int scol = (lane & 3) * 8;

    f32x4 acc[4][4];
#pragma unroll
    for (int i = 0; i < 4; ++i)
#pragma unroll
        for (int j = 0; j < 4; ++j) acc[i][j] = (f32x4)0.f;

    unsigned short* ab0 = &a_lds[0][0] + w * 512;
    unsigned short* ab1 = &a_lds[0][0] + (4 + w) * 512;
    unsigned short* bb0 = &b_lds[0][0] + w * 512;
    unsigned short* bb1 = &b_lds[0][0] + (4 + w) * 512;

    for (int kt = 0; kt < 24; ++kt) {
        const int k0 = kt * 32;
        __syncthreads();
        gl_lds16(&A[(size_t)(m0 + srow) * CDIM + k0 + scol], ab0);
        gl_lds16(&A[(size_t)(m0 + 64 + srow) * CDIM + k0 + scol], ab1);
        gl_lds16(&BT[(size_t)(n0 + srow) * CDIM + k0 + scol], bb0);
        gl_lds16(&BT[(size_t)(n0 + 64 + srow) * CDIM + k0 + scol], bb1);
        __syncthreads();

        bf16x8 afr[4], bfr[4];
#pragma unroll
        for (int i = 0; i < 4; ++i)
            afr[i] = *(const bf16x8*)&a_lds[wm * 64 + i * 16 + lr][kg * 8];
#pragma unroll
        for (int j = 0; j < 4; ++j)
            bfr[j] = *(const bf16x8*)&b_lds[wn * 64 + j * 16 + lr][kg * 8];
#pragma unroll
        for (int i = 0; i < 4; ++i)
#pragma unroll
            for (int j = 0; j < 4; ++j)
                acc[i][j] = __builtin_amdgcn_mfma_f32_16x16x32_bf16(afr[i], bfr[j],
                                                                    acc[i][j], 0, 0, 0);
    }

#pragma unroll
    for (int j = 0; j < 4; ++j) {
        const int c = n0 + wn * 64 + j * 16 + lr;
        const int three = (c >= 1536) ? 2 : ((c >= 768) ? 1 : 0);
        const int rem = c - three * 768;
        const int h = rem >> 6, d = rem & 63;
        const float mul = (three == 0) ? 0.125f : 1.0f;
#pragma unroll
        for (int i = 0; i < 4; ++i) {
#pragma unroll
            for (int rg = 0; rg < 4; ++rg) {
                const int m = m0 + wm * 64 + i * 16 + kg * 4 + rg;
                const int bb = m >> 10, n = m & 1023;
                qkv[(size_t)three * BHND +
                    ((size_t)(bb * NHEADS + h) * SEQ + n) * HDIM + d] =
                    f2bf(acc[i][j][rg] * mul);
            }
        }
    }
}

// ---------------------------------------------------------------------------
// Flash attention v7d = v7b + (1) launch_bounds(256,3): occupancy is grid-
// bound at 3 blocks/CU, so declaring 3 waves/EU is free and raises the
// VGPR budget for deeper load scheduling; (2) vectorized epilogue (us4).
// ---------------------------------------------------------------------------
__global__ __launch_bounds__(256, 3) void attn_kernel7d(const unsigned short* __restrict__ qkv,
                                                        unsigned short* __restrict__ aout) {
    __shared__ unsigned short v_lds[2][64][72];      // [buf][d][key]
    __shared__ unsigned short p_lds[4][2][16][72];   // [wave][tile][q][k]
    const int bh = blockIdx.x;                       // 0..95  (XCD = bh%8)
    const int qt = blockIdx.y;                       // 0..7
    const int t = threadIdx.x, lane = t & 63, w = t >> 6;
    const int lr = lane & 15, kg = lane >> 4;
    const unsigned short* Q = qkv + (size_t)bh * SEQ * HDIM;
    const unsigned short* K = qkv + BHND + (size_t)bh * SEQ * HDIM;
    const unsigned short* V = qkv + 2 * BHND + (size_t)bh * SEQ * HDIM;

    const int qA = qt * 128 + w * 32;
    bf16x8 qfA[2], qfB[2];
#pragma unroll
    for (int ks = 0; ks < 2; ++ks) {
        qfA[ks] = *(const bf16x8*)&Q[(size_t)(qA + lr) * HDIM + ks * 32 + kg * 8];
        qfB[ks] = *(const bf16x8*)&Q[(size_t)(qA + 16 + lr) * HDIM + ks * 32 + kg * 8];
    }

    const int skey = t >> 4, sd4 = (t & 15) * 4;
#pragma unroll
    for (int i = 0; i < 4; ++i) {
        const int key = skey + i * 16;
        us4 vvv = *(const us4*)&V[(size_t)key * HDIM + sd4];
#pragma unroll
        for (int j = 0; j < 4; ++j) v_lds[0][sd4 + j][key] = vvv[j];
    }
    __syncthreads();

    float mA = -1e30f, lA = 0.f, mB = -1e30f, lB = 0.f;
    f32x4 oaccA[4], oaccB[4];
#pragma unroll
    for (int jd = 0; jd < 4; ++jd) { oaccA[jd] = (f32x4)0.f; oaccB[jd] = (f32x4)0.f; }

    for (int kv = 0; kv < 16; ++kv) {
        const int kb = kv * 64;
        if (kv < 15) {
            const int buf = (kv + 1) & 1;
#pragma unroll
            for (int i = 0; i < 4; ++i) {
                const int key = skey + i * 16;
                us4 vvv = *(const us4*)&V[(size_t)(kb + 64 + key) * HDIM + sd4];
#pragma unroll
                for (int j = 0; j < 4; ++j) v_lds[buf][sd4 + j][key] = vvv[j];
            }
        }

        // S^T[k][q] = K·Q^T (K direct from XCD-resident L2)
        f32x4 sA[4], sB[4];
        __builtin_amdgcn_s_setprio(1);
#pragma unroll
        for (int jj = 0; jj < 4; ++jj) {
            sA[jj] = (f32x4)0.f; sB[jj] = (f32x4)0.f;
#pragma unroll
            for (int ks = 0; ks < 2; ++ks) {
                bf16x8 kf = *(const bf16x8*)&K[(size_t)(kb + jj * 16 + lr) * HDIM + ks * 32 + kg * 8];
                sA[jj] = __builtin_amdgcn_mfma_f32_16x16x32_bf16(kf, qfA[ks], sA[jj], 0, 0, 0);
                sB[jj] = __builtin_amdgcn_mfma_f32_16x16x32_bf16(kf, qfB[ks], sB[jj], 0, 0, 0);
            }
        }
        __builtin_amdgcn_s_setprio(0);

        // ---- tile A: max + exp + P-write, then rescale (hides ds_writes) ----
        float corrA, corrB;
        {
            float m0 = fmaxf(fmaxf(sA[0][0], sA[0][1]), fmaxf(sA[0][2], sA[0][3]));
            float m1 = fmaxf(fmaxf(sA[1][0], sA[1][1]), fmaxf(sA[1][2], sA[1][3]));
            float m2 = fmaxf(fmaxf(sA[2][0], sA[2][1]), fmaxf(sA[2][2], sA[2][3]));
            float m3 = fmaxf(fmaxf(sA[3][0], sA[3][1]), fmaxf(sA[3][2], sA[3][3]));
            float mx = fmaxf(fmaxf(m0, m1), fmaxf(m2, m3));
            mx = fmaxf(mx, __shfl_xor(mx, 16, 64));
            mx = fmaxf(mx, __shfl_xor(mx, 32, 64));
            const float mnew = fmaxf(mA, mx);
            corrA = __expf(mA - mnew);
            float rs = 0.f;
#pragma unroll
            for (int jj = 0; jj < 4; ++jj)
#pragma unroll
                for (int r = 0; r < 4; ++r) { sA[jj][r] = __expf(sA[jj][r] - mnew); rs += sA[jj][r]; }
#pragma unroll
            for (int jj = 0; jj < 4; ++jj)
#pragma unroll
                for (int r = 0; r < 4; ++r)
                    p_lds[w][0][lr][jj * 16 + kg * 4 + r] = f2bf(sA[jj][r]);
            rs += __shfl_xor(rs, 16, 64);
            rs += __shfl_xor(rs, 32, 64);
            lA = lA * corrA + rs; mA = mnew;
        }
        {
            float m0 = fmaxf(fmaxf(sB[0][0], sB[0][1]), fmaxf(sB[0][2], sB[0][3]));
            float m1 = fmaxf(fmaxf(sB[1][0], sB[1][1]), fmaxf(sB[1][2], sB[1][3]));
            float m2 = fmaxf(fmaxf(sB[2][0], sB[2][1]), fmaxf(sB[2][2], sB[2][3]));
            float m3 = fmaxf(fmaxf(sB[3][0], sB[3][1]), fmaxf(sB[3][2], sB[3][3]));
            float mx = fmaxf(fmaxf(m0, m1), fmaxf(m2, m3));
            mx = fmaxf(mx, __shfl_xor(mx, 16, 64));
            mx = fmaxf(mx, __shfl_xor(mx, 32, 64));
            const float mnew = fmaxf(mB, mx);
            corrB = __expf(mB - mnew);
            float rs = 0.f;
#pragma unroll
            for (int jj = 0; jj < 4; ++jj)
#pragma unroll
                for (int r = 0; r < 4; ++r) { sB[jj][r] = __expf(sB[jj][r] - mnew); rs += sB[jj][r]; }
#pragma unroll
            for (int jj = 0; jj < 4; ++jj)
#pragma unroll
                for (int r = 0; r < 4; ++r)
                    p_lds[w][1][lr][jj * 16 + kg * 4 + r] = f2bf(sB[jj][r]);
            rs += __shfl_xor(rs, 16, 64);
            rs += __shfl_xor(rs, 32, 64);
            lB = lB * corrB + rs; mB = mnew;
        }
        // rescale oacc while the ds_writes retire
#pragma unroll
        for (int jd = 0; jd < 4; ++jd)
#pragma unroll
            for (int r = 0; r < 4; ++r) { oaccA[jd][r] *= corrA; oaccB[jd][r] *= corrB; }

        asm volatile("s_waitcnt lgkmcnt(0)" ::: "memory");
        __builtin_amdgcn_sched_barrier(0);

        // O^T += V^T · P^T
        const int cb = kv & 1;
        __builtin_amdgcn_s_setprio(1);
#pragma unroll
        for (int c = 0; c < 2; ++c) {
            bf16x8 pfA = *(const bf16x8*)&p_lds[w][0][lr][c * 32 + kg * 8];
            bf16x8 pfB = *(const bf16x8*)&p_lds[w][1][lr][c * 32 + kg * 8];
#pragma unroll
            for (int jd = 0; jd < 4; ++jd) {
                bf16x8 vf = *(const bf16x8*)&v_lds[cb][jd * 16 + lr][c * 32 + kg * 8];
                oaccA[jd] = __builtin_amdgcn_mfma_f32_16x16x32_bf16(vf, pfA, oaccA[jd], 0, 0, 0);
                oaccB[jd] = __builtin_amdgcn_mfma_f32_16x16x32_bf16(vf, pfB, oaccB[jd], 0, 0, 0);
            }
        }
        __builtin_amdgcn_s_setprio(0);

        __syncthreads();
    }

    // vectorized epilogue: d = jd*16 + kg*4 + r is contiguous over r -> us4
    const int bb = bh / NHEADS, h = bh % NHEADS;
    const float invA = 1.0f / lA, invB = 1.0f / lB;
    const size_t rowA = ((size_t)(bb * SEQ + qA + lr)) * CDIM + h * HDIM;
    const size_t rowB = ((size_t)(bb * SEQ + qA + 16 + lr)) * CDIM + h * HDIM;
#pragma unroll
    for (int jd = 0; jd < 4; ++jd) {
        us4 oa, ob;
#pragma unroll
        for (int r = 0; r < 4; ++r) {
            oa[r] = f2bf(oaccA[jd][r] * invA);
            ob[r] = f2bf(oaccB[jd][r] * invB);
        }
        const int d0 = jd * 16 + kg * 4;
        *(us4*)&aout[rowA + d0] = oa;
        *(us4*)&aout[rowB + d0] = ob;
    }
}

// ---------------------------------------------------------------------------
// GEMM2 (m97 structure, XCD swizzle) — R34-proven.
// ---------------------------------------------------------------------------
__global__ __launch_bounds__(256) void proj_gemm2(const unsigned short* __restrict__ A,
                                                  const unsigned short* __restrict__ BT,
                                                  float* __restrict__ out) {
    __shared__ unsigned short a_lds[128][32];
    __shared__ unsigned short b_lds[128][32];
    const int m0 = blockIdx.x * 128;
    const int n0 = blockIdx.y * 128;
    const int t = threadIdx.x, lane = t & 63, w = t >> 6;
    const int wm = w >> 1, wn = w & 1;
    const int lr = lane & 15, kg = lane >> 4;
    const int srow = w * 16 + (lane >> 2);
    const int scol = (lane & 3) * 8;

    f32x4 acc[4][4];
#pragma unroll
    for (int i = 0; i < 4; ++i)
#pragma unroll
        for (int j = 0; j < 4; ++j) acc[i][j] = (f32x4)0.f;

    unsigned short* ab0 = &a_lds[0][0] + w * 512;
    unsigned short* ab1 = &a_lds[0][0] + (4 + w) * 512;
    unsigned short* bb0 = &b_lds[0][0] + w * 512;
    unsigned short* bb1 = &b_lds[0][0] + (4 + w) * 512;

    for (int kt = 0; kt < 24; ++kt) {
        const int k0 = kt * 32;
        __syncthreads();
        gl_lds16(&A[(size_t)(m0 + srow) * CDIM + k0 + scol], ab0);
        gl_lds16(&A[(size_t)(m0 + 64 + srow) * CDIM + k0 + scol], ab1);
        gl_lds16(&BT[(size_t)(n0 + srow) * CDIM + k0 + scol], bb0);
        gl_lds16(&BT[(size_t)(n0 + 64 + srow) * CDIM + k0 + scol], bb1);
        __syncthreads();

        bf16x8 afr[4], bfr[4];
#pragma unroll
        for (int i = 0; i < 4; ++i)
            afr[i] = *(const bf16x8*)&a_lds[wm * 64 + i * 16 + lr][kg * 8];
#pragma unroll
        for (int j = 0; j < 4; ++j)
            bfr[j] = *(const bf16x8*)&b_lds[wn * 64 + j * 16 + lr][kg * 8];
#pragma unroll
        for (int i = 0; i < 4; ++i)
#pragma unroll
            for (int j = 0; j < 4; ++j)
                acc[i][j] = __builtin_amdgcn_mfma_f32_16x16x32_bf16(afr[i], bfr[j],
                                                                    acc[i][j], 0, 0, 0);
    }

#pragma unroll
    for (int i = 0; i < 4; ++i)
#pragma unroll
        for (int j = 0; j < 4; ++j)
#pragma unroll
            for (int rg = 0; rg < 4; ++rg) {
                const int m = m0 + wm * 64 + i * 16 + kg * 4 + rg;
                const int c = n0 + wn * 64 + j * 16 + lr;
                out[(size_t)m * CDIM + c] = acc[i][j][rg];
            }
}

// ---------------------------------------------------------------------------
extern "C" void kernel_launch(void* const* d_in, const int* in_sizes, int n_in,
                              void* d_out, int out_size, void* d_ws, size_t ws_size,
                              hipStream_t stream) {
    const float* x      = (const float*)d_in[0];
    const float* w_qkv  = (const float*)d_in[1];
    const float* w_proj = (const float*)d_in[2];

    unsigned short* qkv  = (unsigned short*)d_ws;
    unsigned short* aout = qkv + 3 * BHND;
    unsigned short* xb   = aout + NX;
    unsigned short* wqt  = xb + NX;
    unsigned short* wpt  = wqt + NWQ;
    float* out = (float*)d_out;

    prep_all<<<3648, 256, 0, stream>>>(x, w_qkv, w_proj, xb, wqt, wpt);
    qkv_gemm2<<<dim3(64, 18), 256, 0, stream>>>(xb, wqt, qkv);
    attn_kernel7d<<<dim3(96, 8), 256, 0, stream>>>(qkv, aout);
    proj_gemm2<<<dim3(64, 6), 256, 0, stream>>>(aout, wpt, out);
}